// Round 6
// baseline (1044.914 us; speedup 1.0000x reference)
//
#include <hip/hip_runtime.h>
#include <hip/hip_bf16.h>
#include <math.h>
#include <stddef.h>

#define NN 8192
#define FF 128
#define HH 512
#define DDIM 256
#define EE 131072
#define ET (2*EE + NN)     // 270336 edges after symmetrize + self loops
#define FEPS 1e-8f

typedef float f32x4 __attribute__((ext_vector_type(4)));
typedef __bf16 bf16x8 __attribute__((ext_vector_type(8)));
typedef unsigned short u16;

static __device__ __forceinline__ u16 f2bf(float f) {
  union { float f; unsigned u; } v; v.f = f;
  return (u16)((v.u + 0x7fffu + ((v.u >> 16) & 1u)) >> 16);
}
static __device__ __forceinline__ float bf2f(u16 h) {
  union { unsigned u; float f; } v; v.u = ((unsigned)h) << 16;
  return v.f;
}
static __device__ __forceinline__ f32x4 mfma16(bf16x8 a, bf16x8 b, f32x4 c) {
  return __builtin_amdgcn_mfma_f32_16x16x32_bf16(a, b, c, 0, 0, 0);
}
// async global->LDS, 16B per lane.
static __device__ __forceinline__ void gload16(const void* g, void* lds) {
  __builtin_amdgcn_global_load_lds(
      (const __attribute__((address_space(1))) void*)(unsigned long long)(uintptr_t)g,
      (__attribute__((address_space(3))) void*)(unsigned int)(uintptr_t)lds,
      16, 0, 0);
}

struct PLF { const float* p[4]; };
struct PLB { const u16* p[6]; int slot[6]; };
struct MB6 { const float* X[6]; const float* Y[6]; int bx[6]; int by[6]; u16* o[6]; };

// ======================= stage 0: global mean/std normalize (fused pair) =======================
__global__ void k_reduce2(const float* __restrict__ xa, const float* __restrict__ xb,
                          int n, double* __restrict__ out) {
  const float* x = blockIdx.y ? xb : xa;
  double* o = out + 2 * blockIdx.y;
  __shared__ double s1[256], s2[256];
  double a = 0.0, b = 0.0;
  for (int i = blockIdx.x * blockDim.x + threadIdx.x; i < n; i += gridDim.x * blockDim.x) {
    double v = (double)x[i];
    a += v; b += v * v;
  }
  s1[threadIdx.x] = a; s2[threadIdx.x] = b;
  __syncthreads();
  for (int w = 128; w > 0; w >>= 1) {
    if (threadIdx.x < w) { s1[threadIdx.x] += s1[threadIdx.x + w]; s2[threadIdx.x] += s2[threadIdx.x + w]; }
    __syncthreads();
  }
  if (threadIdx.x == 0) { atomicAdd(&o[0], s1[0]); atomicAdd(&o[1], s2[0]); }
}

__global__ void k_normalize2(const float* __restrict__ xa, const float* __restrict__ xb,
                             u16* __restrict__ ya, u16* __restrict__ yb, int n,
                             const double* __restrict__ s) {
  const float* x = blockIdx.y ? xb : xa;
  u16* y = blockIdx.y ? yb : ya;
  const double* sp = s + 2 * blockIdx.y;
  double mean = sp[0] / (double)n;
  double var = (sp[1] - (double)n * mean * mean) / (double)(n - 1);  // ddof=1
  float mu = (float)mean;
  float inv = (float)(1.0 / sqrt(var));
  for (int i = blockIdx.x * blockDim.x + threadIdx.x; i < n; i += gridDim.x * blockDim.x)
    y[i] = f2bf((x[i] - mu) * inv);
}

// ======================= GAT: CSR build =======================
__global__ void k_hist(const int* __restrict__ ei, int* __restrict__ deg) {
  int t = blockIdx.x * blockDim.x + threadIdx.x;
  if (t >= ET) return;
  int dst = (t < EE) ? ei[EE + t] : ((t < 2*EE) ? ei[t - EE] : (t - 2*EE));
  atomicAdd(&deg[dst], 1);
}

__global__ void k_scan(const int* __restrict__ deg, int* __restrict__ offs, int* __restrict__ cursor) {
  __shared__ int ts[256];
  int tid = threadIdx.x;
  int loc[32];
  int s = 0;
  #pragma unroll
  for (int i = 0; i < 32; ++i) { loc[i] = s; s += deg[tid * 32 + i]; }
  ts[tid] = s;
  __syncthreads();
  for (int off = 1; off < 256; off <<= 1) {
    int v = (tid >= off) ? ts[tid - off] : 0;
    __syncthreads();
    ts[tid] += v;
    __syncthreads();
  }
  int pre = ts[tid] - s;
  #pragma unroll
  for (int i = 0; i < 32; ++i) {
    int o = pre + loc[i];
    offs[tid * 32 + i] = o;
    cursor[tid * 32 + i] = o;
  }
  if (tid == 255) offs[NN] = ts[255];
}

__global__ void k_scatter(const int* __restrict__ ei, int* __restrict__ cursor, int* __restrict__ srcs) {
  int t = blockIdx.x * blockDim.x + threadIdx.x;
  if (t >= ET) return;
  int src = (t < 2*EE) ? ei[t] : (t - 2*EE);
  int dst = (t < EE) ? ei[EE + t] : ((t < 2*EE) ? ei[t - EE] : (t - 2*EE));
  int pos = atomicAdd(&cursor[dst], 1);
  srcs[pos] = src;
}

// ======================= transpose f32 -> bf16 (optionally squared) =======================
__global__ __launch_bounds__(256) void k_tr_bf16(const float* __restrict__ src, u16* __restrict__ dst,
                                                 int R, int C, int sq) {
  __shared__ float T[32][33];
  int tx = threadIdx.x & 31, ty = threadIdx.x >> 5;
  int r0 = blockIdx.y * 32, c0 = blockIdx.x * 32;
  #pragma unroll
  for (int p = 0; p < 4; ++p)
    T[ty + 8 * p][tx] = src[(size_t)(r0 + ty + 8 * p) * C + c0 + tx];
  __syncthreads();
  #pragma unroll
  for (int p = 0; p < 4; ++p) {
    float v = T[tx][ty + 8 * p];
    if (sq) v *= v;
    dst[(size_t)(c0 + ty + 8 * p) * R + r0 + tx] = f2bf(v);
  }
}

// fused pair transpose for h1/h2 (R=NN, C=DDIM)
__global__ __launch_bounds__(256) void k_tr2(const float* __restrict__ s1, u16* __restrict__ d1,
                                             const float* __restrict__ s2, u16* __restrict__ d2) {
  __shared__ float T[32][33];
  const float* src = blockIdx.z ? s2 : s1;
  u16* dst = blockIdx.z ? d2 : d1;
  int tx = threadIdx.x & 31, ty = threadIdx.x >> 5;
  int r0 = blockIdx.y * 32, c0 = blockIdx.x * 32;
  #pragma unroll
  for (int p = 0; p < 4; ++p)
    T[ty + 8 * p][tx] = src[(size_t)(r0 + ty + 8 * p) * DDIM + c0 + tx];
  __syncthreads();
  #pragma unroll
  for (int p = 0; p < 4; ++p)
    dst[(size_t)(c0 + ty + 8 * p) * NN + r0 + tx] = f2bf(T[tx][ty + 8 * p]);
}

// ======================= MFMA GEMM with fused attention-dot epilogue =======================
// C[M,N] = A[M,K] @ Bt[N,K]^T -> Cb (bf16). If as_ != null: hs[row] += sum_c C*as_[c] etc.
__global__ __launch_bounds__(256) void k_gemm_bf(const u16* __restrict__ A, const u16* __restrict__ Bt,
                                                 u16* __restrict__ Cb, int K, int N,
                                                 const float* __restrict__ as_, const float* __restrict__ ad_,
                                                 float* __restrict__ hs, float* __restrict__ hd) {
  int w = threadIdx.x >> 6, l = threadIdx.x & 63, r15 = l & 15, g = l >> 4;
  int i0 = blockIdx.y * 64 + w * 16;
  int n0 = blockIdx.x * 128;
  f32x4 zero = {0.f, 0.f, 0.f, 0.f};
  f32x4 acc[8];
  #pragma unroll
  for (int n = 0; n < 8; ++n) acc[n] = zero;
  int kcN = K >> 5;
  const u16* arow = A + (size_t)(i0 + r15) * K + g * 8;
  for (int kc = 0; kc < kcN; ++kc) {
    bf16x8 a = *reinterpret_cast<const bf16x8*>(arow + kc * 32);
    #pragma unroll
    for (int n = 0; n < 8; ++n) {
      bf16x8 b = *reinterpret_cast<const bf16x8*>(Bt + (size_t)(n0 + n * 16 + r15) * K + kc * 32 + g * 8);
      acc[n] = mfma16(a, b, acc[n]);
    }
  }
  int io = i0 + g * 4;
  #pragma unroll
  for (int n = 0; n < 8; ++n) {
    int c = n0 + n * 16 + r15;
    #pragma unroll
    for (int q = 0; q < 4; ++q)
      Cb[(size_t)(io + q) * N + c] = f2bf(acc[n][q]);
  }
  if (as_) {
    float hsum[4] = {0.f, 0.f, 0.f, 0.f}, dsum[4] = {0.f, 0.f, 0.f, 0.f};
    #pragma unroll
    for (int n = 0; n < 8; ++n) {
      int c = n0 + n * 16 + r15;
      float av = as_[c], dv = ad_[c];
      #pragma unroll
      for (int q = 0; q < 4; ++q) { hsum[q] += acc[n][q] * av; dsum[q] += acc[n][q] * dv; }
    }
    #pragma unroll
    for (int q = 0; q < 4; ++q) {
      #pragma unroll
      for (int o = 1; o < 16; o <<= 1) { hsum[q] += __shfl_xor(hsum[q], o); dsum[q] += __shfl_xor(dsum[q], o); }
    }
    if (r15 == 0) {
      #pragma unroll
      for (int q = 0; q < 4; ++q) {
        atomicAdd(&hs[io + q], hsum[q]);
        atomicAdd(&hd[io + q], dsum[q]);
      }
    }
  }
}

// ======================= GAT: attention =======================
__global__ void k_alpha(const int* __restrict__ offs, const int* __restrict__ srcs,
                        const float* __restrict__ hs, const float* __restrict__ hd,
                        float* __restrict__ alpha) {
  int wid = (blockIdx.x * blockDim.x + threadIdx.x) >> 6;
  int lane = threadIdx.x & 63;
  if (wid >= NN) return;
  int b = offs[wid], e = offs[wid + 1];
  float hdn = hd[wid];
  float m = -3.4e38f;
  for (int p = b + lane; p < e; p += 64) {
    float v = hs[srcs[p]] + hdn;
    v = v > 0.f ? v : 0.2f * v;        // leaky_relu 0.2
    alpha[p] = v;
    m = fmaxf(m, v);
  }
  #pragma unroll
  for (int o = 32; o > 0; o >>= 1) m = fmaxf(m, __shfl_xor(m, o));
  float den = 0.f;
  for (int p = b + lane; p < e; p += 64) {
    float ex = expf(alpha[p] - m);
    alpha[p] = ex;
    den += ex;
  }
  #pragma unroll
  for (int o = 32; o > 0; o >>= 1) den += __shfl_xor(den, o);
  float sc = 1.f / (den + 1e-16f);
  for (int p = b + lane; p < e; p += 64) alpha[p] *= sc;
}

// wave-per-edge aggregate with 16B vector gathers; 4-wave LDS reduce
__global__ __launch_bounds__(256) void k_agg2(const int* __restrict__ offs, const int* __restrict__ srcs,
                                              const float* __restrict__ alpha, const u16* __restrict__ Hb,
                                              float* __restrict__ outF, u16* __restrict__ outB,
                                              int D, int elu) {
  __shared__ float red[4][512];
  int n = blockIdx.x;
  int b = offs[n], e = offs[n + 1];
  int w = threadIdx.x >> 6, lane = threadIdx.x & 63;
  float acc[8];
  #pragma unroll
  for (int j = 0; j < 8; ++j) acc[j] = 0.f;
  if (D == 512) {
    const u16* base = Hb + lane * 8;
    for (int p = b + w; p < e; p += 4) {
      float a = alpha[p];
      uint4 v = *reinterpret_cast<const uint4*>(base + (size_t)srcs[p] * 512);
      acc[0] += a * bf2f((u16)(v.x & 0xffff)); acc[1] += a * bf2f((u16)(v.x >> 16));
      acc[2] += a * bf2f((u16)(v.y & 0xffff)); acc[3] += a * bf2f((u16)(v.y >> 16));
      acc[4] += a * bf2f((u16)(v.z & 0xffff)); acc[5] += a * bf2f((u16)(v.z >> 16));
      acc[6] += a * bf2f((u16)(v.w & 0xffff)); acc[7] += a * bf2f((u16)(v.w >> 16));
    }
    #pragma unroll
    for (int j = 0; j < 8; ++j) red[w][lane * 8 + j] = acc[j];
  } else {
    const u16* base = Hb + lane * 4;
    for (int p = b + w; p < e; p += 4) {
      float a = alpha[p];
      uint2 v = *reinterpret_cast<const uint2*>(base + (size_t)srcs[p] * 256);
      acc[0] += a * bf2f((u16)(v.x & 0xffff)); acc[1] += a * bf2f((u16)(v.x >> 16));
      acc[2] += a * bf2f((u16)(v.y & 0xffff)); acc[3] += a * bf2f((u16)(v.y >> 16));
    }
    #pragma unroll
    for (int j = 0; j < 4; ++j) red[w][lane * 4 + j] = acc[j];
  }
  __syncthreads();
  for (int dd = threadIdx.x; dd < D; dd += 256) {
    float sres = red[0][dd] + red[1][dd] + red[2][dd] + red[3][dd];
    if (elu) sres = sres > 0.f ? sres : (expf(sres) - 1.f);
    if (outF) outF[(size_t)n * D + dd] = sres;
    outB[(size_t)n * D + dd] = f2bf(sres);
  }
}

// ======================= mutual: inverse row norms (fused pair) =======================
__global__ void k_rninv2(const float* __restrict__ h1, const float* __restrict__ h2,
                         float* __restrict__ o1, float* __restrict__ o2) {
  const float* h = blockIdx.y ? h2 : h1;
  float* o = blockIdx.y ? o2 : o1;
  int wid = (blockIdx.x * blockDim.x + threadIdx.x) >> 6;
  int lane = threadIdx.x & 63;
  if (wid >= NN) return;
  float4 v = *reinterpret_cast<const float4*>(h + (size_t)wid * DDIM + lane * 4);
  float a = v.x * v.x + v.y * v.y + v.z * v.z + v.w * v.w;
  #pragma unroll
  for (int o2_ = 32; o2_ > 0; o2_ >>= 1) a += __shfl_xor(a, o2_);
  if (!lane) o[wid] = 1.f / sqrtf(a);
}

// ======================= mutual sums: R[i]=sum_j cos, S[j]=sum_i cos =======================
__global__ __launch_bounds__(256, 2) void k_sums_bf(const u16* __restrict__ Ab, const u16* __restrict__ Bb,
                                                    const float* __restrict__ nainv, const float* __restrict__ nbinv,
                                                    float* __restrict__ R, float* __restrict__ S) {
  __shared__ uint4 Bs2[2][2048];
  __shared__ float Scol[2048];
  int tid = threadIdx.x;
  int w = tid >> 6, l = tid & 63, r15 = l & 15, g = l >> 4;
  int i0 = blockIdx.y * 64;
  int jc0 = blockIdx.x * 2048;
  for (int s = tid; s < 2048; s += 256) Scol[s] = 0.f;
  bf16x8 qf[8];
  const u16* arow = Ab + (size_t)(i0 + w * 16 + r15) * 256 + g * 8;
  #pragma unroll
  for (int kc = 0; kc < 8; ++kc) qf[kc] = *reinterpret_cast<const bf16x8*>(arow + kc * 32);
  float ni[4];
  #pragma unroll
  for (int q = 0; q < 4; ++q) ni[q] = nainv[i0 + w * 16 + g * 4 + q];
  int offS[8];
  #pragma unroll
  for (int p = 0; p < 8; ++p) {
    int c = p * 256 + tid;
    int frag = c >> 6, n = frag >> 3, kc = frag & 7;
    int ll = c & 63, gg = ll >> 4, jr = ll & 15;
    offS[p] = (n * 16 + jr) * 256 + kc * 32 + gg * 8;
  }
  auto stage = [&](int buf, int j0) {
    const u16* bs = Bb + (size_t)j0 * 256;
    #pragma unroll
    for (int p = 0; p < 8; ++p)
      gload16(bs + offS[p], &Bs2[buf][p * 256 + tid]);
  };
  float rowacc[4] = {0.f, 0.f, 0.f, 0.f};
  f32x4 zero = {0.f, 0.f, 0.f, 0.f};
  stage(0, jc0);
  __syncthreads();
  int cur = 0;
  for (int t = 0; t < 32; ++t) {
    if (t < 31) stage(cur ^ 1, jc0 + (t + 1) * 64);
    int j0 = jc0 + t * 64;
    f32x4 sacc[4];
    #pragma unroll
    for (int n = 0; n < 4; ++n) sacc[n] = zero;
    #pragma unroll
    for (int kc = 0; kc < 8; ++kc)
      #pragma unroll
      for (int n = 0; n < 4; ++n) {
        bf16x8 b = *reinterpret_cast<const bf16x8*>(&Bs2[cur][(n * 8 + kc) * 64 + l]);
        sacc[n] = mfma16(qf[kc], b, sacc[n]);
      }
    #pragma unroll
    for (int n = 0; n < 4; ++n) {
      float nb = nbinv[j0 + n * 16 + r15];
      float cs = 0.f;
      #pragma unroll
      for (int q = 0; q < 4; ++q) {
        float cv = sacc[n][q] * ni[q] * nb;
        rowacc[q] += cv;
        cs += cv;
      }
      cs += __shfl_xor(cs, 16);
      cs += __shfl_xor(cs, 32);
      if (l < 16) atomicAdd(&Scol[t * 64 + n * 16 + l], cs);
    }
    __syncthreads();
    cur ^= 1;
  }
  #pragma unroll
  for (int q = 0; q < 4; ++q) {
    float v = rowacc[q];
    v += __shfl_xor(v, 1); v += __shfl_xor(v, 2); v += __shfl_xor(v, 4); v += __shfl_xor(v, 8);
    if (r15 == 0) atomicAdd(&R[i0 + w * 16 + g * 4 + q], v);
  }
  for (int s = tid; s < 2048; s += 256) atomicAdd(&S[jc0 + s], Scol[s]);
}

__global__ void k_scj(const float* __restrict__ S, const float* __restrict__ R,
                      const float* __restrict__ n1inv, const float* __restrict__ n2inv,
                      float* __restrict__ scj1, float* __restrict__ scj2) {
  int j = blockIdx.x * blockDim.x + threadIdx.x;
  if (j >= NN) return;
  scj1[j] = n2inv[j] / S[j];
  scj2[j] = n1inv[j] / R[j];
}

// ======================= mutual apply (flash, MFMA, gload_lds dbuf, 128i x 32j tiles) =======================
// Out[i,:] += sum_j (dot(A_i,B_j)*nainv[i]*scj[j]) * B[j,:].  grid (8, 64), block 256.
// Each wave owns 32 i-rows (2 A-frag sets) -> every LDS b-read feeds 2 MFMAs.
__global__ __launch_bounds__(256, 2) void k_apply_bf(const u16* __restrict__ Ab, const u16* __restrict__ Bb,
                                                     const u16* __restrict__ Btg, const float* __restrict__ nainv,
                                                     const float* __restrict__ scj, float* __restrict__ Out) {
  __shared__ uint4 Bs2[2][1024];              // B[j][k] frags, 16KB/buf
  __shared__ uint4 Bt2[2][1024];              // B^T frags, 16KB/buf
  __shared__ __align__(16) u16 Ps[4 * 32 * 36];  // per-wave P tile 32x32 (pad 36)
  int tid = threadIdx.x;
  int w = tid >> 6, l = tid & 63, r15 = l & 15, g = l >> 4;
  int i0 = blockIdx.y * 128;
  int jc0 = blockIdx.x * 1024;
  bf16x8 qf[2][8];
  #pragma unroll
  for (int s = 0; s < 2; ++s) {
    const u16* arow = Ab + (size_t)(i0 + w * 32 + s * 16 + r15) * 256 + g * 8;
    #pragma unroll
    for (int kc = 0; kc < 8; ++kc) qf[s][kc] = *reinterpret_cast<const bf16x8*>(arow + kc * 32);
  }
  float ni[2][4];
  #pragma unroll
  for (int s = 0; s < 2; ++s)
    #pragma unroll
    for (int q = 0; q < 4; ++q) ni[s][q] = nainv[i0 + w * 32 + s * 16 + g * 4 + q];
  int offS[4], offT[4];
  #pragma unroll
  for (int p = 0; p < 4; ++p) {
    int c = p * 256 + tid;
    int ll = c & 63, gg = ll >> 4, jr = ll & 15;
    int frag = c >> 6;                  // 0..15
    int n = frag >> 3, kc = frag & 7;   // Bs: 2 j-subtiles x 8 kc
    offS[p] = (n * 16 + jr) * 256 + kc * 32 + gg * 8;
    offT[p] = (frag * 16 + jr) * NN + gg * 8;   // Bt: 16 d-subtiles, k=j (32 wide)
  }
  auto stage = [&](int buf, int j0) {
    const u16* bs = Bb + (size_t)j0 * 256;
    const u16* ts = Btg + (size_t)j0;
    #pragma unroll
    for (int p = 0; p < 4; ++p) {
      gload16(bs + offS[p], &Bs2[buf][p * 256 + tid]);
      gload16(ts + offT[p], &Bt2[buf][p * 256 + tid]);
    }
  };
  f32x4 zero = {0.f, 0.f, 0.f, 0.f};
  f32x4 oacc[2][16];
  #pragma unroll
  for (int s = 0; s < 2; ++s)
    #pragma unroll
    for (int n = 0; n < 16; ++n) oacc[s][n] = zero;
  u16* PsW = Ps + w * 32 * 36;
  stage(0, jc0);
  __syncthreads();
  int cur = 0;
  for (int t = 0; t < 32; ++t) {
    if (t < 31) stage(cur ^ 1, jc0 + (t + 1) * 32);   // in flight during compute
    int j0 = jc0 + t * 32;
    // QK: scores for this wave's 32 rows x 32 j (each b-read feeds 2 MFMAs)
    f32x4 sacc[2][2];
    sacc[0][0] = zero; sacc[0][1] = zero; sacc[1][0] = zero; sacc[1][1] = zero;
    #pragma unroll
    for (int kc = 0; kc < 8; ++kc)
      #pragma unroll
      for (int n = 0; n < 2; ++n) {
        bf16x8 b = *reinterpret_cast<const bf16x8*>(&Bs2[cur][(n * 8 + kc) * 64 + l]);
        sacc[0][n] = mfma16(qf[0][kc], b, sacc[0][n]);
        sacc[1][n] = mfma16(qf[1][kc], b, sacc[1][n]);
      }
    // scale -> per-wave P tile (bf16) in LDS
    #pragma unroll
    for (int n = 0; n < 2; ++n) {
      float sc = scj[j0 + n * 16 + r15];
      #pragma unroll
      for (int s = 0; s < 2; ++s)
        #pragma unroll
        for (int q = 0; q < 4; ++q) {
          float val = sacc[s][n][q] * ni[s][q] * sc;
          PsW[(s * 16 + g * 4 + q) * 36 + n * 16 + r15] = f2bf(val);
        }
    }
    // PV: oacc[s][i, d] += P[i, j] * B[j, d]   (single K=32 step; b shared by 2 MFMAs)
    {
      bf16x8 pa0 = *reinterpret_cast<const bf16x8*>(PsW + r15 * 36 + g * 8);
      bf16x8 pa1 = *reinterpret_cast<const bf16x8*>(PsW + (16 + r15) * 36 + g * 8);
      #pragma unroll
      for (int n2 = 0; n2 < 16; ++n2) {
        bf16x8 b = *reinterpret_cast<const bf16x8*>(&Bt2[cur][n2 * 64 + l]);
        oacc[0][n2] = mfma16(pa0, b, oacc[0][n2]);
        oacc[1][n2] = mfma16(pa1, b, oacc[1][n2]);
      }
    }
    __syncthreads();   // drains vmcnt: next buffer staged & all reads of cur done
    cur ^= 1;
  }
  #pragma unroll
  for (int s = 0; s < 2; ++s) {
    int io = i0 + w * 32 + s * 16 + g * 4;
    #pragma unroll
    for (int n2 = 0; n2 < 16; ++n2) {
      int c = n2 * 16 + r15;
      #pragma unroll
      for (int q = 0; q < 4; ++q)
        atomicAdd(&Out[(size_t)(io + q) * 256 + c], oacc[s][n2][q]);
    }
  }
}

// ======================= match (fused prep, MFMA, bf16 out, batched x6) =======================
__global__ __launch_bounds__(256) void k_match_b6(MB6 M, const u16* __restrict__ W2t) {
  int z = blockIdx.z;
  const float* X = M.X[z];
  const float* Y = M.Y[z];
  int bx = M.bx[z], by = M.by[z];
  u16* outb = M.o[z];
  int w = threadIdx.x >> 6, l = threadIdx.x & 63, r15 = l & 15, g = l >> 4;
  int i0 = blockIdx.y * 64 + w * 16;
  int n0 = blockIdx.x * 128;
  f32x4 zero = {0.f, 0.f, 0.f, 0.f};
  f32x4 aU[8], aP[8], aQ[8];
  #pragma unroll
  for (int n = 0; n < 8; ++n) { aU[n] = zero; aP[n] = zero; aQ[n] = zero; }
  int row = i0 + r15;
  const float* xr = X + (size_t)(bx ? 0 : row) * 256;
  const float* yr = Y + (size_t)(by ? 0 : row) * 256;
  #pragma unroll 2
  for (int kc = 0; kc < 8; ++kc) {
    int base = kc * 32 + g * 8;
    float4 x0 = *reinterpret_cast<const float4*>(xr + base);
    float4 x1 = *reinterpret_cast<const float4*>(xr + base + 4);
    float4 y0 = *reinterpret_cast<const float4*>(yr + base);
    float4 y1 = *reinterpret_cast<const float4*>(yr + base + 4);
    bf16x8 fu, fp, fq;
    fu[0] = (__bf16)(x0.x * y0.x); fu[1] = (__bf16)(x0.y * y0.y);
    fu[2] = (__bf16)(x0.z * y0.z); fu[3] = (__bf16)(x0.w * y0.w);
    fu[4] = (__bf16)(x1.x * y1.x); fu[5] = (__bf16)(x1.y * y1.y);
    fu[6] = (__bf16)(x1.z * y1.z); fu[7] = (__bf16)(x1.w * y1.w);
    fp[0] = (__bf16)(x0.x * x0.x); fp[1] = (__bf16)(x0.y * x0.y);
    fp[2] = (__bf16)(x0.z * x0.z); fp[3] = (__bf16)(x0.w * x0.w);
    fp[4] = (__bf16)(x1.x * x1.x); fp[5] = (__bf16)(x1.y * x1.y);
    fp[6] = (__bf16)(x1.z * x1.z); fp[7] = (__bf16)(x1.w * x1.w);
    fq[0] = (__bf16)(y0.x * y0.x); fq[1] = (__bf16)(y0.y * y0.y);
    fq[2] = (__bf16)(y0.z * y0.z); fq[3] = (__bf16)(y0.w * y0.w);
    fq[4] = (__bf16)(y1.x * y1.x); fq[5] = (__bf16)(y1.y * y1.y);
    fq[6] = (__bf16)(y1.z * y1.z); fq[7] = (__bf16)(y1.w * y1.w);
    #pragma unroll
    for (int n = 0; n < 8; ++n) {
      bf16x8 b = *reinterpret_cast<const bf16x8*>(W2t + (size_t)(n0 + n * 16 + r15) * 256 + kc * 32 + g * 8);
      aU[n] = mfma16(fu, b, aU[n]);
      aP[n] = mfma16(fp, b, aP[n]);
      aQ[n] = mfma16(fq, b, aQ[n]);
    }
  }
  int io = i0 + g * 4;
  #pragma unroll
  for (int n = 0; n < 8; ++n) {
    int c = n0 + n * 16 + r15;
    #pragma unroll
    for (int q = 0; q < 4; ++q) {
      float s = sqrtf(aP[n][q]) * sqrtf(aQ[n][q]);
      outb[(size_t)(io + q) * 256 + c] = f2bf(aU[n][q] / fmaxf(s, FEPS));
    }
  }
}

// ======================= scalar match pair (om1/om2: 1x256 each) =======================
__global__ void k_match_g(const float* __restrict__ X1, const float* __restrict__ Y1,
                          const float* __restrict__ X2, const float* __restrict__ Y2,
                          const float* __restrict__ W2, float* __restrict__ v) {
  __shared__ float u[256], p[256], q[256];
  const float* X = blockIdx.x ? X2 : X1;
  const float* Y = blockIdx.x ? Y2 : Y1;
  float* o = v + (blockIdx.x ? 1792 : 768);
  int t = threadIdx.x;
  float xv = X[t], yv = Y[t];
  u[t] = xv * yv; p[t] = xv * xv; q[t] = yv * yv;
  __syncthreads();
  float a = 0.f, b = 0.f, c = 0.f;
  #pragma unroll 4
  for (int d = 0; d < 256; ++d) {
    float wv = W2[(size_t)d * DDIM + t];
    a += u[d] * wv; b += p[d] * wv; c += q[d] * wv;
  }
  o[t] = a / fmaxf(sqrtf(b) * sqrtf(c), FEPS);
}

__global__ void k_w2(const float* __restrict__ Wm, float* __restrict__ W2, int n) {
  int i = blockIdx.x * blockDim.x + threadIdx.x;
  if (i < n) { float v = Wm[i]; W2[i] = v * v; }
}

// ======================= batched readouts =======================
__global__ void k_bmu_f(PLF L, float* __restrict__ mu) {
  const float* h = L.p[blockIdx.y];
  int d = threadIdx.x;
  int r0 = blockIdx.x * 128;
  float acc = 0.f;
  for (int r = 0; r < 128; ++r) acc += h[(size_t)(r0 + r) * 256 + d];
  atomicAdd(&mu[blockIdx.y * 256 + d], acc);
}

__global__ void k_bmu_b(PLB L, float* __restrict__ mu) {
  const u16* h = L.p[blockIdx.y];
  int d = threadIdx.x;
  int r0 = blockIdx.x * 128;
  float acc = 0.f;
  for (int r = 0; r < 128; ++r) acc += bf2f(h[(size_t)(r0 + r) * 256 + d]);
  atomicAdd(&mu[blockIdx.y * 256 + d], acc);
}

__global__ void k_bgv(const float* __restrict__ mu, const float* __restrict__ Wr,
                      float* __restrict__ g) {
  __shared__ float ls[256];
  int m = blockIdx.x, t = threadIdx.x;
  ls[t] = mu[m * 256 + t] * (1.f / (float)NN);
  __syncthreads();
  float acc = 0.f;
  #pragma unroll 4
  for (int d = 0; d < 256; ++d) acc += ls[d] * Wr[(size_t)d * 256 + t];
  g[m * 256 + t] = tanhf(acc);
}

__global__ __launch_bounds__(256) void k_bsc_f(PLF L, const float* __restrict__ g,
                                               float* __restrict__ ogbase) {
  __shared__ __align__(16) float gs[256];
  __shared__ float sarr[32];
  int m = blockIdx.y;
  const float* h = L.p[m];
  int t = threadIdx.x, w = t >> 6, l = t & 63;
  gs[t] = g[m * 256 + t];
  __syncthreads();
  int r0 = blockIdx.x * 32;
  float4 gv4 = reinterpret_cast<const float4*>(gs)[l];
  for (int rr = w * 8; rr < w * 8 + 8; ++rr) {
    float4 hv = reinterpret_cast<const float4*>(h + (size_t)(r0 + rr) * 256)[l];
    float dot = hv.x * gv4.x + hv.y * gv4.y + hv.z * gv4.z + hv.w * gv4.w;
    #pragma unroll
    for (int o = 32; o > 0; o >>= 1) dot += __shfl_xor(dot, o);
    if (!l) sarr[rr] = 1.f / (1.f + expf(-dot));
  }
  __syncthreads();
  float acc = 0.f;
  for (int rr = 0; rr < 32; ++rr) acc += sarr[rr] * h[(size_t)(r0 + rr) * 256 + t];
  atomicAdd(&ogbase[m * 256 + t], acc);
}

__global__ __launch_bounds__(256) void k_bsc_b(PLB L, const float* __restrict__ g,
                                               float* __restrict__ v) {
  __shared__ __align__(16) float gs[256];
  __shared__ float sarr[32];
  int m = blockIdx.y;
  const u16* h = L.p[m];
  int t = threadIdx.x, w = t >> 6, l = t & 63;
  gs[t] = g[m * 256 + t];
  __syncthreads();
  int r0 = blockIdx.x * 32;
  float4 gv4 = reinterpret_cast<const float4*>(gs)[l];
  for (int rr = w * 8; rr < w * 8 + 8; ++rr) {
    ushort4 hv = *reinterpret_cast<const ushort4*>(h + (size_t)(r0 + rr) * 256 + l * 4);
    float dot = bf2f(hv.x) * gv4.x + bf2f(hv.y) * gv4.y + bf2f(hv.z) * gv4.z + bf2f(hv.w) * gv4.w;
    #pragma unroll
    for (int o = 32; o > 0; o >>= 1) dot += __shfl_xor(dot, o);
    if (!l) sarr[rr] = 1.f / (1.f + expf(-dot));
  }
  __syncthreads();
  float acc = 0.f;
  for (int rr = 0; rr < 32; ++rr) acc += sarr[rr] * bf2f(h[(size_t)(r0 + rr) * 256 + t]);
  atomicAdd(&v[L.slot[m] + t], acc);
}

// ======================= MLP (split-K parallel GEMV) =======================
__global__ void k_binit(const float* __restrict__ b1, const float* __restrict__ b2,
                        const float* __restrict__ b3, float* __restrict__ l1,
                        float* __restrict__ l2, float* __restrict__ l3) {
  int t = blockIdx.x * 256 + threadIdx.x;
  if (t < 512) l1[t] = b1[t];
  if (t < 256) l2[t] = b2[t];
  if (t < 128) l3[t] = b3[t];
}

__global__ void k_gemv(const float* __restrict__ vin, const float* __restrict__ w,
                       float* __restrict__ out, int K, int M, int Kc, int relu_in) {
  int m = blockIdx.x * 256 + threadIdx.x;
  if (m >= M) return;
  int k0 = blockIdx.y * Kc;
  float acc = 0.f;
  #pragma unroll 4
  for (int k = k0; k < k0 + Kc; ++k) {
    float x = vin[k];
    if (relu_in) x = fmaxf(x, 0.f);
    acc += x * w[(size_t)k * M + m];
  }
  atomicAdd(&out[m], acc);
}

__global__ void k_final(const float* __restrict__ l3, const float* __restrict__ w4,
                        const float* __restrict__ b4, const int* __restrict__ label,
                        float* __restrict__ out) {
  __shared__ float ls[128];
  int t = threadIdx.x;
  ls[t] = fmaxf(l3[t], 0.f) * w4[t];
  __syncthreads();
  for (int w = 64; w > 0; w >>= 1) { if (t < w) ls[t] += ls[t + w]; __syncthreads(); }
  if (t == 0) {
    float z = 1.f / (1.f + expf(-(ls[0] + b4[0])));
    out[0] = z;
    float lb = (float)label[0];
    out[1] = lb;
    out[2] = expf(-lb);
  }
}

// ======================= host =======================
extern "C" void kernel_launch(void* const* d_in, const int* in_sizes, int n_in,
                              void* d_out, int out_size, void* d_ws, size_t ws_size,
                              hipStream_t stream) {
  (void)in_sizes; (void)n_in; (void)out_size;
  const float* x_s   = (const float*)d_in[0];
  const float* x_t   = (const float*)d_in[1];
  const int*   ei_s  = (const int*)d_in[2];
  const int*   ei_t  = (const int*)d_in[3];
  const int*   label = (const int*)d_in[4];
  const float* W_g1  = (const float*)d_in[5];
  const float* a1s   = (const float*)d_in[6];
  const float* a1d   = (const float*)d_in[7];
  const float* W_g2  = (const float*)d_in[8];
  const float* a2s   = (const float*)d_in[9];
  const float* a2d   = (const float*)d_in[10];
  const float* W_read  = (const float*)d_in[11];
  const float* W_match = (const float*)d_in[12];
  const float* w1 = (const float*)d_in[13]; const float* b1 = (const float*)d_in[14];
  const float* w2 = (const float*)d_in[15]; const float* b2 = (const float*)d_in[16];
  const float* w3 = (const float*)d_in[17]; const float* b3 = (const float*)d_in[18];
  const float* w4 = (const float*)d_in[19]; const float* b4 = (const float*)d_in[20];
  float* out = (float*)d_out;

  char* base = (char*)d_ws;
  size_t off = 0;
  auto alloc = [&](size_t bytes) -> void* {
    void* pp = base + off;
    off = (off + bytes + 255) & ~(size_t)255;
    return pp;
  };
  double* dsum = (double*)alloc(4 * sizeof(double));
  u16*   hb_bf= (u16*)alloc((size_t)NN * HH * 2);
  u16*   aggb = (u16*)alloc((size_t)NN * HH * 2);
  float* h1   = (float*)alloc((size_t)NN * DDIM * 4);
  float* h2   = (float*)alloc((size_t)NN * DDIM * 4);
  float* h1m  = (float*)alloc((size_t)NN * DDIM * 4);   // h1m,h2m adjacent: one memset
  float* h2m  = (float*)alloc((size_t)NN * DDIM * 4);
  u16*   f1b  = (u16*)alloc((size_t)NN * FF * 2);
  u16*   f2b  = (u16*)alloc((size_t)NN * FF * 2);
  u16*   h1b  = (u16*)alloc((size_t)NN * DDIM * 2);
  u16*   h2b  = (u16*)alloc((size_t)NN * DDIM * 2);
  u16*   h1t  = (u16*)alloc((size_t)NN * DDIM * 2);
  u16*   h2t  = (u16*)alloc((size_t)NN * DDIM * 2);
  u16*   mb0  = (u16*)alloc((size_t)NN * DDIM * 2);
  u16*   mb1  = (u16*)alloc((size_t)NN * DDIM * 2);
  u16*   mb2  = (u16*)alloc((size_t)NN * DDIM * 2);
  u16*   mb3  = (u16*)alloc((size_t)NN * DDIM * 2);
  u16*   mb4  = (u16*)alloc((size_t)NN * DDIM * 2);
  u16*   mb5  = (u16*)alloc((size_t)NN * DDIM * 2);
  float* alpha= (float*)alloc((size_t)ET * 4);
  int*   srcs = (int*)alloc((size_t)ET * 4);
  int*   deg  = (int*)alloc(NN * 4);
  int*   curs = (int*)alloc(NN * 4);
  int*   offs = (int*)alloc((NN + 1) * 4);
  float* n1inv= (float*)alloc(NN * 4);
  float* n2inv= (float*)alloc(NN * 4);
  float* Rr   = (float*)alloc(NN * 4);      // Rr,Ss adjacent: one memset
  float* Ss   = (float*)alloc(NN * 4);
  float* scj1 = (float*)alloc(NN * 4);
  float* scj2 = (float*)alloc(NN * 4);
  float* hsb  = (float*)alloc(NN * 4);      // hsb,hdb adjacent: one memset
  float* hdb  = (float*)alloc(NN * 4);
  float* W2   = (float*)alloc((size_t)DDIM * DDIM * 4);
  u16*   Wg1t = (u16*)alloc((size_t)HH * FF * 2);
  u16*   Wg2t = (u16*)alloc((size_t)DDIM * HH * 2);
  u16*   W2t  = (u16*)alloc((size_t)DDIM * DDIM * 2);
  // small zeroed region (one memset): mug1|ogs|mug2|v
  float* mug1 = (float*)alloc(4 * 256 * 4);
  float* ogs  = (float*)alloc(4 * 256 * 4);
  float* mug2 = (float*)alloc(6 * 256 * 4);
  float* v    = (float*)alloc(2048 * 4);
  float* g1   = (float*)alloc(4 * 256 * 4);
  float* g2   = (float*)alloc(6 * 256 * 4);
  float* l1o  = (float*)alloc(512 * 4);
  float* l2o  = (float*)alloc(256 * 4);
  float* l3o  = (float*)alloc(128 * 4);
  if (off > ws_size) return;

  float* h1g  = ogs + 0;
  float* h2g  = ogs + 256;
  float* h1mg = ogs + 512;
  float* h2mg = ogs + 768;

  // ---- stage 0 ----
  hipMemsetAsync(dsum, 0, 4 * sizeof(double), stream);
  k_reduce2<<<dim3(1024, 2), 256, 0, stream>>>(x_s, x_t, NN * FF, dsum);
  k_normalize2<<<dim3(1024, 2), 256, 0, stream>>>(x_s, x_t, f1b, f2b, NN * FF, dsum);

  // ---- weight preps ----
  k_tr_bf16<<<dim3(HH / 32, FF / 32), 256, 0, stream>>>(W_g1, Wg1t, FF, HH, 0);
  k_tr_bf16<<<dim3(DDIM / 32, HH / 32), 256, 0, stream>>>(W_g2, Wg2t, HH, DDIM, 0);
  k_tr_bf16<<<dim3(DDIM / 32, DDIM / 32), 256, 0, stream>>>(W_match, W2t, DDIM, DDIM, 1);
  k_w2<<<dim3((DDIM * DDIM + 255) / 256), 256, 0, stream>>>(W_match, W2, DDIM * DDIM);

  // ---- GAT ----
  auto run_gat = [&](const u16* finb, const int* ei, float* hout, u16* houtb) {
    hipMemsetAsync(deg, 0, NN * 4, stream);
    k_hist<<<dim3((ET + 255) / 256), 256, 0, stream>>>(ei, deg);
    k_scan<<<1, 256, 0, stream>>>(deg, offs, curs);
    k_scatter<<<dim3((ET + 255) / 256), 256, 0, stream>>>(ei, curs, srcs);
    hipMemsetAsync(hsb, 0, 2 * NN * 4, stream);
    k_gemm_bf<<<dim3(HH / 128, NN / 64), 256, 0, stream>>>(finb, Wg1t, hb_bf, FF, HH, a1s, a1d, hsb, hdb);
    k_alpha<<<dim3(NN / 4), 256, 0, stream>>>(offs, srcs, hsb, hdb, alpha);
    k_agg2<<<dim3(NN), 256, 0, stream>>>(offs, srcs, alpha, hb_bf, nullptr, aggb, HH, 1);
    hipMemsetAsync(hsb, 0, 2 * NN * 4, stream);
    k_gemm_bf<<<dim3(DDIM / 128, NN / 64), 256, 0, stream>>>(aggb, Wg2t, hb_bf, HH, DDIM, a2s, a2d, hsb, hdb);
    k_alpha<<<dim3(NN / 4), 256, 0, stream>>>(offs, srcs, hsb, hdb, alpha);
    k_agg2<<<dim3(NN), 256, 0, stream>>>(offs, srcs, alpha, hb_bf, hout, houtb, DDIM, 0);
  };
  run_gat(f1b, ei_s, h1, h1b);
  run_gat(f2b, ei_t, h2, h2b);

  // ---- mutual ----
  k_rninv2<<<dim3(NN / 4, 2), 256, 0, stream>>>(h1, h2, n1inv, n2inv);
  k_tr2<<<dim3(DDIM / 32, NN / 32, 2), 256, 0, stream>>>(h1, h1t, h2, h2t);
  hipMemsetAsync(Rr, 0, 2 * NN * 4, stream);
  k_sums_bf<<<dim3(4, NN / 64), 256, 0, stream>>>(h1b, h2b, n1inv, n2inv, Rr, Ss);
  k_scj<<<dim3(NN / 256), 256, 0, stream>>>(Ss, Rr, n1inv, n2inv, scj1, scj2);
  hipMemsetAsync(h1m, 0, 2 * (size_t)NN * DDIM * 4, stream);
  k_apply_bf<<<dim3(8, NN / 128), 256, 0, stream>>>(h1b, h2b, h2t, n1inv, scj1, h1m);
  k_apply_bf<<<dim3(8, NN / 128), 256, 0, stream>>>(h2b, h1b, h1t, n2inv, scj2, h2m);

  // zero small region: mug1|ogs|mug2|v  (contiguous, 256B-aligned sizes)
  hipMemsetAsync(mug1, 0, (4 * 256 + 4 * 256 + 6 * 256 + 2048) * 4, stream);

  // ---- readout group 1: h1, h2, h1m, h2m ----
  PLF g1l; g1l.p[0] = h1; g1l.p[1] = h2; g1l.p[2] = h1m; g1l.p[3] = h2m;
  k_bmu_f<<<dim3(64, 4), 256, 0, stream>>>(g1l, mug1);
  k_bgv<<<dim3(4), 256, 0, stream>>>(mug1, W_read, g1);
  k_bsc_f<<<dim3(256, 4), 256, 0, stream>>>(g1l, g1, ogs);

  // ---- matches (batched) ----
  MB6 m6;
  m6.X[0] = h1;  m6.Y[0] = h1m;  m6.bx[0] = 0; m6.by[0] = 0; m6.o[0] = mb0;
  m6.X[1] = h1;  m6.Y[1] = h1mg; m6.bx[1] = 0; m6.by[1] = 1; m6.o[1] = mb1;
  m6.X[2] = h1g; m6.Y[2] = h1m;  m6.bx[2] = 1; m6.by[2] = 0; m6.o[2] = mb2;
  m6.X[3] = h2;  m6.Y[3] = h2m;  m6.bx[3] = 0; m6.by[3] = 0; m6.o[3] = mb3;
  m6.X[4] = h2;  m6.Y[4] = h2mg; m6.bx[4] = 0; m6.by[4] = 1; m6.o[4] = mb4;
  m6.X[5] = h2g; m6.Y[5] = h2m;  m6.bx[5] = 1; m6.by[5] = 0; m6.o[5] = mb5;
  k_match_b6<<<dim3(2, NN / 64, 6), 256, 0, stream>>>(m6, W2t);
  k_match_g<<<dim3(2), 256, 0, stream>>>(h1g, h1mg, h2g, h2mg, W2, v);

  // ---- readout group 2: 6 bf16 match outputs -> v slots ----
  PLB g2l;
  g2l.p[0] = mb0; g2l.slot[0] = 0;
  g2l.p[1] = mb1; g2l.slot[1] = 256;
  g2l.p[2] = mb2; g2l.slot[2] = 512;
  g2l.p[3] = mb3; g2l.slot[3] = 1024;
  g2l.p[4] = mb4; g2l.slot[4] = 1280;
  g2l.p[5] = mb5; g2l.slot[5] = 1536;
  k_bmu_b<<<dim3(64, 6), 256, 0, stream>>>(g2l, mug2);
  k_bgv<<<dim3(6), 256, 0, stream>>>(mug2, W_read, g2);
  k_bsc_b<<<dim3(256, 6), 256, 0, stream>>>(g2l, g2, v);

  // ---- MLP (split-K gemv) ----
  k_binit<<<dim3(2), 256, 0, stream>>>(b1, b2, b3, l1o, l2o, l3o);
  k_gemv<<<dim3(2, 16), 256, 0, stream>>>(v, w1, l1o, 2048, 512, 128, 0);
  k_gemv<<<dim3(1, 8), 256, 0, stream>>>(l1o, w2, l2o, 512, 256, 64, 1);
  k_gemv<<<dim3(1, 8), 256, 0, stream>>>(l2o, w3, l3o, 256, 128, 32, 1);
  k_final<<<1, 128, 0, stream>>>(l3o, w4, b4, label, out);
}

// Round 7
// 711.693 us; speedup vs baseline: 1.4682x; 1.4682x over previous
//
#include <hip/hip_runtime.h>
#include <hip/hip_bf16.h>
#include <math.h>
#include <stddef.h>

#define NN 8192
#define FF 128
#define HH 512
#define DDIM 256
#define EE 131072
#define ET (2*EE + NN)     // 270336 edges after symmetrize + self loops
#define FEPS 1e-8f

typedef float f32x4 __attribute__((ext_vector_type(4)));
typedef __bf16 bf16x8 __attribute__((ext_vector_type(8)));
typedef unsigned short u16;

static __device__ __forceinline__ u16 f2bf(float f) {
  union { float f; unsigned u; } v; v.f = f;
  return (u16)((v.u + 0x7fffu + ((v.u >> 16) & 1u)) >> 16);
}
static __device__ __forceinline__ float bf2f(u16 h) {
  union { unsigned u; float f; } v; v.u = ((unsigned)h) << 16;
  return v.f;
}
static __device__ __forceinline__ f32x4 mfma16(bf16x8 a, bf16x8 b, f32x4 c) {
  return __builtin_amdgcn_mfma_f32_16x16x32_bf16(a, b, c, 0, 0, 0);
}

struct PLF { const float* p[4]; };
struct PLB { const u16* p[6]; int slot[6]; };
struct MB6 { const float* X[6]; const float* Y[6]; int bx[6]; int by[6]; u16* o[6]; };

// ======================= stage 0: global mean/std normalize (fused pair) =======================
__global__ void k_reduce2(const float* __restrict__ xa, const float* __restrict__ xb,
                          int n, double* __restrict__ out) {
  const float* x = blockIdx.y ? xb : xa;
  double* o = out + 2 * blockIdx.y;
  __shared__ double s1[256], s2[256];
  double a = 0.0, b = 0.0;
  for (int i = blockIdx.x * blockDim.x + threadIdx.x; i < n; i += gridDim.x * blockDim.x) {
    double v = (double)x[i];
    a += v; b += v * v;
  }
  s1[threadIdx.x] = a; s2[threadIdx.x] = b;
  __syncthreads();
  for (int w = 128; w > 0; w >>= 1) {
    if (threadIdx.x < w) { s1[threadIdx.x] += s1[threadIdx.x + w]; s2[threadIdx.x] += s2[threadIdx.x + w]; }
    __syncthreads();
  }
  if (threadIdx.x == 0) { atomicAdd(&o[0], s1[0]); atomicAdd(&o[1], s2[0]); }
}

__global__ void k_normalize2(const float* __restrict__ xa, const float* __restrict__ xb,
                             u16* __restrict__ ya, u16* __restrict__ yb, int n,
                             const double* __restrict__ s) {
  const float* x = blockIdx.y ? xb : xa;
  u16* y = blockIdx.y ? yb : ya;
  const double* sp = s + 2 * blockIdx.y;
  double mean = sp[0] / (double)n;
  double var = (sp[1] - (double)n * mean * mean) / (double)(n - 1);  // ddof=1
  float mu = (float)mean;
  float inv = (float)(1.0 / sqrt(var));
  for (int i = blockIdx.x * blockDim.x + threadIdx.x; i < n; i += gridDim.x * blockDim.x)
    y[i] = f2bf((x[i] - mu) * inv);
}

// ======================= GAT: CSR build =======================
__global__ void k_hist(const int* __restrict__ ei, int* __restrict__ deg) {
  int t = blockIdx.x * blockDim.x + threadIdx.x;
  if (t >= ET) return;
  int dst = (t < EE) ? ei[EE + t] : ((t < 2*EE) ? ei[t - EE] : (t - 2*EE));
  atomicAdd(&deg[dst], 1);
}

__global__ void k_scan(const int* __restrict__ deg, int* __restrict__ offs, int* __restrict__ cursor) {
  __shared__ int ts[256];
  int tid = threadIdx.x;
  int loc[32];
  int s = 0;
  #pragma unroll
  for (int i = 0; i < 32; ++i) { loc[i] = s; s += deg[tid * 32 + i]; }
  ts[tid] = s;
  __syncthreads();
  for (int off = 1; off < 256; off <<= 1) {
    int v = (tid >= off) ? ts[tid - off] : 0;
    __syncthreads();
    ts[tid] += v;
    __syncthreads();
  }
  int pre = ts[tid] - s;
  #pragma unroll
  for (int i = 0; i < 32; ++i) {
    int o = pre + loc[i];
    offs[tid * 32 + i] = o;
    cursor[tid * 32 + i] = o;
  }
  if (tid == 255) offs[NN] = ts[255];
}

__global__ void k_scatter(const int* __restrict__ ei, int* __restrict__ cursor, int* __restrict__ srcs) {
  int t = blockIdx.x * blockDim.x + threadIdx.x;
  if (t >= ET) return;
  int src = (t < 2*EE) ? ei[t] : (t - 2*EE);
  int dst = (t < EE) ? ei[EE + t] : ((t < 2*EE) ? ei[t - EE] : (t - 2*EE));
  int pos = atomicAdd(&cursor[dst], 1);
  srcs[pos] = src;
}

// ======================= transpose f32 -> bf16 (optionally squared) =======================
__global__ __launch_bounds__(256) void k_tr_bf16(const float* __restrict__ src, u16* __restrict__ dst,
                                                 int R, int C, int sq) {
  __shared__ float T[32][33];
  int tx = threadIdx.x & 31, ty = threadIdx.x >> 5;
  int r0 = blockIdx.y * 32, c0 = blockIdx.x * 32;
  #pragma unroll
  for (int p = 0; p < 4; ++p)
    T[ty + 8 * p][tx] = src[(size_t)(r0 + ty + 8 * p) * C + c0 + tx];
  __syncthreads();
  #pragma unroll
  for (int p = 0; p < 4; ++p) {
    float v = T[tx][ty + 8 * p];
    if (sq) v *= v;
    dst[(size_t)(c0 + ty + 8 * p) * R + r0 + tx] = f2bf(v);
  }
}

// fused pair transpose+scale: z=0: (hA, scA) -> tA (plain), wA (scaled); z=1: (hB, scB) -> tB, wB
__global__ __launch_bounds__(256) void k_tr2w(const float* __restrict__ hA, const float* __restrict__ scA,
                                              u16* __restrict__ tA, u16* __restrict__ wA,
                                              const float* __restrict__ hB, const float* __restrict__ scB,
                                              u16* __restrict__ tB, u16* __restrict__ wB) {
  __shared__ float T[32][33];
  __shared__ float W[32][33];
  const float* src = blockIdx.z ? hB : hA;
  const float* sc  = blockIdx.z ? scB : scA;
  u16* dt = blockIdx.z ? tB : tA;
  u16* dw = blockIdx.z ? wB : wA;
  int tx = threadIdx.x & 31, ty = threadIdx.x >> 5;
  int r0 = blockIdx.y * 32, c0 = blockIdx.x * 32;
  #pragma unroll
  for (int p = 0; p < 4; ++p) {
    int j = r0 + ty + 8 * p;
    float v = src[(size_t)j * DDIM + c0 + tx];
    T[ty + 8 * p][tx] = v;
    W[ty + 8 * p][tx] = v * sc[j];
  }
  __syncthreads();
  #pragma unroll
  for (int p = 0; p < 4; ++p) {
    size_t o = (size_t)(c0 + ty + 8 * p) * NN + r0 + tx;
    dt[o] = f2bf(T[tx][ty + 8 * p]);
    dw[o] = f2bf(W[tx][ty + 8 * p]);
  }
}

// ======================= MFMA GEMM with fused attention-dot epilogue =======================
__global__ __launch_bounds__(256) void k_gemm_bf(const u16* __restrict__ A, const u16* __restrict__ Bt,
                                                 u16* __restrict__ Cb, int K, int N,
                                                 const float* __restrict__ as_, const float* __restrict__ ad_,
                                                 float* __restrict__ hs, float* __restrict__ hd) {
  int w = threadIdx.x >> 6, l = threadIdx.x & 63, r15 = l & 15, g = l >> 4;
  int i0 = blockIdx.y * 64 + w * 16;
  int n0 = blockIdx.x * 128;
  f32x4 zero = {0.f, 0.f, 0.f, 0.f};
  f32x4 acc[8];
  #pragma unroll
  for (int n = 0; n < 8; ++n) acc[n] = zero;
  int kcN = K >> 5;
  const u16* arow = A + (size_t)(i0 + r15) * K + g * 8;
  for (int kc = 0; kc < kcN; ++kc) {
    bf16x8 a = *reinterpret_cast<const bf16x8*>(arow + kc * 32);
    #pragma unroll
    for (int n = 0; n < 8; ++n) {
      bf16x8 b = *reinterpret_cast<const bf16x8*>(Bt + (size_t)(n0 + n * 16 + r15) * K + kc * 32 + g * 8);
      acc[n] = mfma16(a, b, acc[n]);
    }
  }
  int io = i0 + g * 4;
  #pragma unroll
  for (int n = 0; n < 8; ++n) {
    int c = n0 + n * 16 + r15;
    #pragma unroll
    for (int q = 0; q < 4; ++q)
      Cb[(size_t)(io + q) * N + c] = f2bf(acc[n][q]);
  }
  if (as_) {
    float hsum[4] = {0.f, 0.f, 0.f, 0.f}, dsum[4] = {0.f, 0.f, 0.f, 0.f};
    #pragma unroll
    for (int n = 0; n < 8; ++n) {
      int c = n0 + n * 16 + r15;
      float av = as_[c], dv = ad_[c];
      #pragma unroll
      for (int q = 0; q < 4; ++q) { hsum[q] += acc[n][q] * av; dsum[q] += acc[n][q] * dv; }
    }
    #pragma unroll
    for (int q = 0; q < 4; ++q) {
      #pragma unroll
      for (int o = 1; o < 16; o <<= 1) { hsum[q] += __shfl_xor(hsum[q], o); dsum[q] += __shfl_xor(dsum[q], o); }
    }
    if (r15 == 0) {
      #pragma unroll
      for (int q = 0; q < 4; ++q) {
        atomicAdd(&hs[io + q], hsum[q]);
        atomicAdd(&hd[io + q], dsum[q]);
      }
    }
  }
}

// ======================= GAT: attention =======================
__global__ void k_alpha(const int* __restrict__ offs, const int* __restrict__ srcs,
                        const float* __restrict__ hs, const float* __restrict__ hd,
                        float* __restrict__ alpha) {
  int wid = (blockIdx.x * blockDim.x + threadIdx.x) >> 6;
  int lane = threadIdx.x & 63;
  if (wid >= NN) return;
  int b = offs[wid], e = offs[wid + 1];
  float hdn = hd[wid];
  float m = -3.4e38f;
  for (int p = b + lane; p < e; p += 64) {
    float v = hs[srcs[p]] + hdn;
    v = v > 0.f ? v : 0.2f * v;        // leaky_relu 0.2
    alpha[p] = v;
    m = fmaxf(m, v);
  }
  #pragma unroll
  for (int o = 32; o > 0; o >>= 1) m = fmaxf(m, __shfl_xor(m, o));
  float den = 0.f;
  for (int p = b + lane; p < e; p += 64) {
    float ex = expf(alpha[p] - m);
    alpha[p] = ex;
    den += ex;
  }
  #pragma unroll
  for (int o = 32; o > 0; o >>= 1) den += __shfl_xor(den, o);
  float sc = 1.f / (den + 1e-16f);
  for (int p = b + lane; p < e; p += 64) alpha[p] *= sc;
}

// wave-per-edge aggregate with 16B vector gathers; 4-wave LDS reduce
__global__ __launch_bounds__(256) void k_agg2(const int* __restrict__ offs, const int* __restrict__ srcs,
                                              const float* __restrict__ alpha, const u16* __restrict__ Hb,
                                              float* __restrict__ outF, u16* __restrict__ outB,
                                              int D, int elu) {
  __shared__ float red[4][512];
  int n = blockIdx.x;
  int b = offs[n], e = offs[n + 1];
  int w = threadIdx.x >> 6, lane = threadIdx.x & 63;
  float acc[8];
  #pragma unroll
  for (int j = 0; j < 8; ++j) acc[j] = 0.f;
  if (D == 512) {
    const u16* base = Hb + lane * 8;
    for (int p = b + w; p < e; p += 4) {
      float a = alpha[p];
      uint4 v = *reinterpret_cast<const uint4*>(base + (size_t)srcs[p] * 512);
      acc[0] += a * bf2f((u16)(v.x & 0xffff)); acc[1] += a * bf2f((u16)(v.x >> 16));
      acc[2] += a * bf2f((u16)(v.y & 0xffff)); acc[3] += a * bf2f((u16)(v.y >> 16));
      acc[4] += a * bf2f((u16)(v.z & 0xffff)); acc[5] += a * bf2f((u16)(v.z >> 16));
      acc[6] += a * bf2f((u16)(v.w & 0xffff)); acc[7] += a * bf2f((u16)(v.w >> 16));
    }
    #pragma unroll
    for (int j = 0; j < 8; ++j) red[w][lane * 8 + j] = acc[j];
  } else {
    const u16* base = Hb + lane * 4;
    for (int p = b + w; p < e; p += 4) {
      float a = alpha[p];
      uint2 v = *reinterpret_cast<const uint2*>(base + (size_t)srcs[p] * 256);
      acc[0] += a * bf2f((u16)(v.x & 0xffff)); acc[1] += a * bf2f((u16)(v.x >> 16));
      acc[2] += a * bf2f((u16)(v.y & 0xffff)); acc[3] += a * bf2f((u16)(v.y >> 16));
    }
    #pragma unroll
    for (int j = 0; j < 4; ++j) red[w][lane * 4 + j] = acc[j];
  }
  __syncthreads();
  for (int dd = threadIdx.x; dd < D; dd += 256) {
    float sres = red[0][dd] + red[1][dd] + red[2][dd] + red[3][dd];
    if (elu) sres = sres > 0.f ? sres : (expf(sres) - 1.f);
    if (outF) outF[(size_t)n * D + dd] = sres;
    outB[(size_t)n * D + dd] = f2bf(sres);
  }
}

// ======================= mutual: inverse row norms (fused pair) =======================
__global__ void k_rninv2(const float* __restrict__ h1, const float* __restrict__ h2,
                         float* __restrict__ o1, float* __restrict__ o2) {
  const float* h = blockIdx.y ? h2 : h1;
  float* o = blockIdx.y ? o2 : o1;
  int wid = (blockIdx.x * blockDim.x + threadIdx.x) >> 6;
  int lane = threadIdx.x & 63;
  if (wid >= NN) return;
  float4 v = *reinterpret_cast<const float4*>(h + (size_t)wid * DDIM + lane * 4);
  float a = v.x * v.x + v.y * v.y + v.z * v.z + v.w * v.w;
  #pragma unroll
  for (int o2_ = 32; o2_ > 0; o2_ >>= 1) a += __shfl_xor(a, o2_);
  if (!lane) o[wid] = 1.f / sqrtf(a);
}

// ======================= mutual rank-1 sums =======================
// y=0: ut[0:256]   = u[d] = sum_i n1inv[i]*h1[i][d]
// y=1: ut[256:512] = t[d] = sum_j n2inv[j]*h2[j][d]
__global__ void k_wsum(const float* __restrict__ h1, const float* __restrict__ h2,
                       const float* __restrict__ n1inv, const float* __restrict__ n2inv,
                       float* __restrict__ ut) {
  const float* h = blockIdx.y ? h2 : h1;
  const float* wv = blockIdx.y ? n2inv : n1inv;
  float* o = ut + 256 * blockIdx.y;
  int d = threadIdx.x;
  int r0 = blockIdx.x * 128;
  float acc = 0.f;
  for (int r = 0; r < 128; ++r) acc += wv[r0 + r] * h[(size_t)(r0 + r) * 256 + d];
  atomicAdd(&o[d], acc);
}

// y=0: R[i] = n1inv[i]*dot(h1_i, t=ut+256); y=1: S[j] = n2inv[j]*dot(h2_j, u=ut+0)
__global__ void k_rs(const float* __restrict__ h1, const float* __restrict__ h2,
                     const float* __restrict__ n1inv, const float* __restrict__ n2inv,
                     const float* __restrict__ ut, float* __restrict__ R, float* __restrict__ S) {
  const float* h  = blockIdx.y ? h2 : h1;
  const float* ni = blockIdx.y ? n2inv : n1inv;
  const float* gv = blockIdx.y ? ut : ut + 256;
  float* o = blockIdx.y ? S : R;
  int wid = (blockIdx.x * blockDim.x + threadIdx.x) >> 6;
  int lane = threadIdx.x & 63;
  if (wid >= NN) return;
  float4 v = *reinterpret_cast<const float4*>(h + (size_t)wid * 256 + lane * 4);
  float4 g4 = *reinterpret_cast<const float4*>(gv + lane * 4);
  float a = v.x * g4.x + v.y * g4.y + v.z * g4.z + v.w * g4.w;
  #pragma unroll
  for (int o2_ = 32; o2_ > 0; o2_ >>= 1) a += __shfl_xor(a, o2_);
  if (!lane) o[wid] = ni[wid] * a;
}

__global__ void k_scj(const float* __restrict__ S, const float* __restrict__ R,
                      const float* __restrict__ n1inv, const float* __restrict__ n2inv,
                      float* __restrict__ scj1, float* __restrict__ scj2) {
  int j = blockIdx.x * blockDim.x + threadIdx.x;
  if (j >= NN) return;
  scj1[j] = n2inv[j] / S[j];
  scj2[j] = n1inv[j] / R[j];
}

// ======================= M = h^T diag(w) h  (256x256, split-K MFMA) =======================
// z&1 selects matrix: mat0: A=wh2t, Bt=h2t -> Mf[0]; mat1: A=wh1t, Bt=h1t -> Mf[1]
// z>>1 selects K-chunk (16 chunks x 512 K). grid (2, 4, 32), block 256.
__global__ __launch_bounds__(256) void k_gemm_M(const u16* __restrict__ A1, const u16* __restrict__ B1,
                                                const u16* __restrict__ A2, const u16* __restrict__ B2,
                                                float* __restrict__ Mf) {
  int mat = blockIdx.z & 1, kch = blockIdx.z >> 1;
  const u16* A = mat ? A2 : A1;
  const u16* Bt = mat ? B2 : B1;
  float* C = Mf + mat * 65536;
  int w = threadIdx.x >> 6, l = threadIdx.x & 63, r15 = l & 15, g = l >> 4;
  int i0 = blockIdx.y * 64 + w * 16;
  int n0 = blockIdx.x * 128;
  f32x4 zero = {0.f, 0.f, 0.f, 0.f};
  f32x4 acc[8];
  #pragma unroll
  for (int n = 0; n < 8; ++n) acc[n] = zero;
  const u16* arow = A + (size_t)(i0 + r15) * NN + g * 8;
  for (int kc = kch * 16; kc < kch * 16 + 16; ++kc) {
    bf16x8 a = *reinterpret_cast<const bf16x8*>(arow + kc * 32);
    #pragma unroll
    for (int n = 0; n < 8; ++n) {
      bf16x8 b = *reinterpret_cast<const bf16x8*>(Bt + (size_t)(n0 + n * 16 + r15) * NN + kc * 32 + g * 8);
      acc[n] = mfma16(a, b, acc[n]);
    }
  }
  int io = i0 + g * 4;
  #pragma unroll
  for (int n = 0; n < 8; ++n) {
    int c = n0 + n * 16 + r15;
    #pragma unroll
    for (int q = 0; q < 4; ++q)
      atomicAdd(&C[(size_t)(io + q) * 256 + c], acc[n][q]);
  }
}

__global__ void k_m2bf(const float* __restrict__ Mf, u16* __restrict__ Mb) {
  size_t o = (size_t)blockIdx.y * 65536 + blockIdx.x * 256 + threadIdx.x;
  Mb[o] = f2bf(Mf[o]);
}

// ======================= hXm = diag(sc) * (hXb @ M^T)  (M symmetric) =======================
// grid (2, 128, 2), block 256.
__global__ __launch_bounds__(256) void k_gemm_hm(const u16* __restrict__ A1, const u16* __restrict__ M1,
                                                 const float* __restrict__ s1, float* __restrict__ O1,
                                                 const u16* __restrict__ A2, const u16* __restrict__ M2,
                                                 const float* __restrict__ s2, float* __restrict__ O2) {
  int z = blockIdx.z;
  const u16* A = z ? A2 : A1;
  const u16* Bt = z ? M2 : M1;
  const float* sc = z ? s2 : s1;
  float* O = z ? O2 : O1;
  int w = threadIdx.x >> 6, l = threadIdx.x & 63, r15 = l & 15, g = l >> 4;
  int i0 = blockIdx.y * 64 + w * 16;
  int n0 = blockIdx.x * 128;
  f32x4 zero = {0.f, 0.f, 0.f, 0.f};
  f32x4 acc[8];
  #pragma unroll
  for (int n = 0; n < 8; ++n) acc[n] = zero;
  const u16* arow = A + (size_t)(i0 + r15) * 256 + g * 8;
  #pragma unroll
  for (int kc = 0; kc < 8; ++kc) {
    bf16x8 a = *reinterpret_cast<const bf16x8*>(arow + kc * 32);
    #pragma unroll
    for (int n = 0; n < 8; ++n) {
      bf16x8 b = *reinterpret_cast<const bf16x8*>(Bt + (size_t)(n0 + n * 16 + r15) * 256 + kc * 32 + g * 8);
      acc[n] = mfma16(a, b, acc[n]);
    }
  }
  int io = i0 + g * 4;
  float s4[4];
  #pragma unroll
  for (int q = 0; q < 4; ++q) s4[q] = sc[io + q];
  #pragma unroll
  for (int n = 0; n < 8; ++n) {
    int c = n0 + n * 16 + r15;
    #pragma unroll
    for (int q = 0; q < 4; ++q)
      O[(size_t)(io + q) * 256 + c] = acc[n][q] * s4[q];
  }
}

// ======================= match (fused prep, MFMA, bf16 out, batched x6) =======================
__global__ __launch_bounds__(256) void k_match_b6(MB6 M, const u16* __restrict__ W2t) {
  int z = blockIdx.z;
  const float* X = M.X[z];
  const float* Y = M.Y[z];
  int bx = M.bx[z], by = M.by[z];
  u16* outb = M.o[z];
  int w = threadIdx.x >> 6, l = threadIdx.x & 63, r15 = l & 15, g = l >> 4;
  int i0 = blockIdx.y * 64 + w * 16;
  int n0 = blockIdx.x * 128;
  f32x4 zero = {0.f, 0.f, 0.f, 0.f};
  f32x4 aU[8], aP[8], aQ[8];
  #pragma unroll
  for (int n = 0; n < 8; ++n) { aU[n] = zero; aP[n] = zero; aQ[n] = zero; }
  int row = i0 + r15;
  const float* xr = X + (size_t)(bx ? 0 : row) * 256;
  const float* yr = Y + (size_t)(by ? 0 : row) * 256;
  #pragma unroll 2
  for (int kc = 0; kc < 8; ++kc) {
    int base = kc * 32 + g * 8;
    float4 x0 = *reinterpret_cast<const float4*>(xr + base);
    float4 x1 = *reinterpret_cast<const float4*>(xr + base + 4);
    float4 y0 = *reinterpret_cast<const float4*>(yr + base);
    float4 y1 = *reinterpret_cast<const float4*>(yr + base + 4);
    bf16x8 fu, fp, fq;
    fu[0] = (__bf16)(x0.x * y0.x); fu[1] = (__bf16)(x0.y * y0.y);
    fu[2] = (__bf16)(x0.z * y0.z); fu[3] = (__bf16)(x0.w * y0.w);
    fu[4] = (__bf16)(x1.x * y1.x); fu[5] = (__bf16)(x1.y * y1.y);
    fu[6] = (__bf16)(x1.z * y1.z); fu[7] = (__bf16)(x1.w * y1.w);
    fp[0] = (__bf16)(x0.x * x0.x); fp[1] = (__bf16)(x0.y * x0.y);
    fp[2] = (__bf16)(x0.z * x0.z); fp[3] = (__bf16)(x0.w * x0.w);
    fp[4] = (__bf16)(x1.x * x1.x); fp[5] = (__bf16)(x1.y * x1.y);
    fp[6] = (__bf16)(x1.z * x1.z); fp[7] = (__bf16)(x1.w * x1.w);
    fq[0] = (__bf16)(y0.x * y0.x); fq[1] = (__bf16)(y0.y * y0.y);
    fq[2] = (__bf16)(y0.z * y0.z); fq[3] = (__bf16)(y0.w * y0.w);
    fq[4] = (__bf16)(y1.x * y1.x); fq[5] = (__bf16)(y1.y * y1.y);
    fq[6] = (__bf16)(y1.z * y1.z); fq[7] = (__bf16)(y1.w * y1.w);
    #pragma unroll
    for (int n = 0; n < 8; ++n) {
      bf16x8 b = *reinterpret_cast<const bf16x8*>(W2t + (size_t)(n0 + n * 16 + r15) * 256 + kc * 32 + g * 8);
      aU[n] = mfma16(fu, b, aU[n]);
      aP[n] = mfma16(fp, b, aP[n]);
      aQ[n] = mfma16(fq, b, aQ[n]);
    }
  }
  int io = i0 + g * 4;
  #pragma unroll
  for (int n = 0; n < 8; ++n) {
    int c = n0 + n * 16 + r15;
    #pragma unroll
    for (int q = 0; q < 4; ++q) {
      float s = sqrtf(aP[n][q]) * sqrtf(aQ[n][q]);
      outb[(size_t)(io + q) * 256 + c] = f2bf(aU[n][q] / fmaxf(s, FEPS));
    }
  }
}

// ======================= scalar match pair (om1/om2: 1x256 each) =======================
__global__ void k_match_g(const float* __restrict__ X1, const float* __restrict__ Y1,
                          const float* __restrict__ X2, const float* __restrict__ Y2,
                          const float* __restrict__ W2, float* __restrict__ v) {
  __shared__ float u[256], p[256], q[256];
  const float* X = blockIdx.x ? X2 : X1;
  const float* Y = blockIdx.x ? Y2 : Y1;
  float* o = v + (blockIdx.x ? 1792 : 768);
  int t = threadIdx.x;
  float xv = X[t], yv = Y[t];
  u[t] = xv * yv; p[t] = xv * xv; q[t] = yv * yv;
  __syncthreads();
  float a = 0.f, b = 0.f, c = 0.f;
  #pragma unroll 4
  for (int d = 0; d < 256; ++d) {
    float wv = W2[(size_t)d * DDIM + t];
    a += u[d] * wv; b += p[d] * wv; c += q[d] * wv;
  }
  o[t] = a / fmaxf(sqrtf(b) * sqrtf(c), FEPS);
}

__global__ void k_w2(const float* __restrict__ Wm, float* __restrict__ W2, int n) {
  int i = blockIdx.x * blockDim.x + threadIdx.x;
  if (i < n) { float v = Wm[i]; W2[i] = v * v; }
}

// ======================= batched readouts =======================
__global__ void k_bmu_f(PLF L, float* __restrict__ mu) {
  const float* h = L.p[blockIdx.y];
  int d = threadIdx.x;
  int r0 = blockIdx.x * 128;
  float acc = 0.f;
  for (int r = 0; r < 128; ++r) acc += h[(size_t)(r0 + r) * 256 + d];
  atomicAdd(&mu[blockIdx.y * 256 + d], acc);
}

__global__ void k_bmu_b(PLB L, float* __restrict__ mu) {
  const u16* h = L.p[blockIdx.y];
  int d = threadIdx.x;
  int r0 = blockIdx.x * 128;
  float acc = 0.f;
  for (int r = 0; r < 128; ++r) acc += bf2f(h[(size_t)(r0 + r) * 256 + d]);
  atomicAdd(&mu[blockIdx.y * 256 + d], acc);
}

__global__ void k_bgv(const float* __restrict__ mu, const float* __restrict__ Wr,
                      float* __restrict__ g) {
  __shared__ float ls[256];
  int m = blockIdx.x, t = threadIdx.x;
  ls[t] = mu[m * 256 + t] * (1.f / (float)NN);
  __syncthreads();
  float acc = 0.f;
  #pragma unroll 4
  for (int d = 0; d < 256; ++d) acc += ls[d] * Wr[(size_t)d * 256 + t];
  g[m * 256 + t] = tanhf(acc);
}

__global__ __launch_bounds__(256) void k_bsc_f(PLF L, const float* __restrict__ g,
                                               float* __restrict__ ogbase) {
  __shared__ __align__(16) float gs[256];
  __shared__ float sarr[32];
  int m = blockIdx.y;
  const float* h = L.p[m];
  int t = threadIdx.x, w = t >> 6, l = t & 63;
  gs[t] = g[m * 256 + t];
  __syncthreads();
  int r0 = blockIdx.x * 32;
  float4 gv4 = reinterpret_cast<const float4*>(gs)[l];
  for (int rr = w * 8; rr < w * 8 + 8; ++rr) {
    float4 hv = reinterpret_cast<const float4*>(h + (size_t)(r0 + rr) * 256)[l];
    float dot = hv.x * gv4.x + hv.y * gv4.y + hv.z * gv4.z + hv.w * gv4.w;
    #pragma unroll
    for (int o = 32; o > 0; o >>= 1) dot += __shfl_xor(dot, o);
    if (!l) sarr[rr] = 1.f / (1.f + expf(-dot));
  }
  __syncthreads();
  float acc = 0.f;
  for (int rr = 0; rr < 32; ++rr) acc += sarr[rr] * h[(size_t)(r0 + rr) * 256 + t];
  atomicAdd(&ogbase[m * 256 + t], acc);
}

__global__ __launch_bounds__(256) void k_bsc_b(PLB L, const float* __restrict__ g,
                                               float* __restrict__ v) {
  __shared__ __align__(16) float gs[256];
  __shared__ float sarr[32];
  int m = blockIdx.y;
  const u16* h = L.p[m];
  int t = threadIdx.x, w = t >> 6, l = t & 63;
  gs[t] = g[m * 256 + t];
  __syncthreads();
  int r0 = blockIdx.x * 32;
  float4 gv4 = reinterpret_cast<const float4*>(gs)[l];
  for (int rr = w * 8; rr < w * 8 + 8; ++rr) {
    ushort4 hv = *reinterpret_cast<const ushort4*>(h + (size_t)(r0 + rr) * 256 + l * 4);
    float dot = bf2f(hv.x) * gv4.x + bf2f(hv.y) * gv4.y + bf2f(hv.z) * gv4.z + bf2f(hv.w) * gv4.w;
    #pragma unroll
    for (int o = 32; o > 0; o >>= 1) dot += __shfl_xor(dot, o);
    if (!l) sarr[rr] = 1.f / (1.f + expf(-dot));
  }
  __syncthreads();
  float acc = 0.f;
  for (int rr = 0; rr < 32; ++rr) acc += sarr[rr] * bf2f(h[(size_t)(r0 + rr) * 256 + t]);
  atomicAdd(&v[L.slot[m] + t], acc);
}

// ======================= MLP (split-K parallel GEMV) =======================
__global__ void k_binit(const float* __restrict__ b1, const float* __restrict__ b2,
                        const float* __restrict__ b3, float* __restrict__ l1,
                        float* __restrict__ l2, float* __restrict__ l3) {
  int t = blockIdx.x * 256 + threadIdx.x;
  if (t < 512) l1[t] = b1[t];
  if (t < 256) l2[t] = b2[t];
  if (t < 128) l3[t] = b3[t];
}

__global__ void k_gemv(const float* __restrict__ vin, const float* __restrict__ w,
                       float* __restrict__ out, int K, int M, int Kc, int relu_in) {
  int m = blockIdx.x * 256 + threadIdx.x;
  if (m >= M) return;
  int k0 = blockIdx.y * Kc;
  float acc = 0.f;
  #pragma unroll 4
  for (int k = k0; k < k0 + Kc; ++k) {
    float x = vin[k];
    if (relu_in) x = fmaxf(x, 0.f);
    acc += x * w[(size_t)k * M + m];
  }
  atomicAdd(&out[m], acc);
}

__global__ void k_final(const float* __restrict__ l3, const float* __restrict__ w4,
                        const float* __restrict__ b4, const int* __restrict__ label,
                        float* __restrict__ out) {
  __shared__ float ls[128];
  int t = threadIdx.x;
  ls[t] = fmaxf(l3[t], 0.f) * w4[t];
  __syncthreads();
  for (int w = 64; w > 0; w >>= 1) { if (t < w) ls[t] += ls[t + w]; __syncthreads(); }
  if (t == 0) {
    float z = 1.f / (1.f + expf(-(ls[0] + b4[0])));
    out[0] = z;
    float lb = (float)label[0];
    out[1] = lb;
    out[2] = expf(-lb);
  }
}

// ======================= host =======================
extern "C" void kernel_launch(void* const* d_in, const int* in_sizes, int n_in,
                              void* d_out, int out_size, void* d_ws, size_t ws_size,
                              hipStream_t stream) {
  (void)in_sizes; (void)n_in; (void)out_size;
  const float* x_s   = (const float*)d_in[0];
  const float* x_t   = (const float*)d_in[1];
  const int*   ei_s  = (const int*)d_in[2];
  const int*   ei_t  = (const int*)d_in[3];
  const int*   label = (const int*)d_in[4];
  const float* W_g1  = (const float*)d_in[5];
  const float* a1s   = (const float*)d_in[6];
  const float* a1d   = (const float*)d_in[7];
  const float* W_g2  = (const float*)d_in[8];
  const float* a2s   = (const float*)d_in[9];
  const float* a2d   = (const float*)d_in[10];
  const float* W_read  = (const float*)d_in[11];
  const float* W_match = (const float*)d_in[12];
  const float* w1 = (const float*)d_in[13]; const float* b1 = (const float*)d_in[14];
  const float* w2 = (const float*)d_in[15]; const float* b2 = (const float*)d_in[16];
  const float* w3 = (const float*)d_in[17]; const float* b3 = (const float*)d_in[18];
  const float* w4 = (const float*)d_in[19]; const float* b4 = (const float*)d_in[20];
  float* out = (float*)d_out;

  char* base = (char*)d_ws;
  size_t off = 0;
  auto alloc = [&](size_t bytes) -> void* {
    void* pp = base + off;
    off = (off + bytes + 255) & ~(size_t)255;
    return pp;
  };
  double* dsum = (double*)alloc(4 * sizeof(double));
  u16*   hb_bf= (u16*)alloc((size_t)NN * HH * 2);
  u16*   aggb = (u16*)alloc((size_t)NN * HH * 2);
  float* h1   = (float*)alloc((size_t)NN * DDIM * 4);
  float* h2   = (float*)alloc((size_t)NN * DDIM * 4);
  float* h1m  = (float*)alloc((size_t)NN * DDIM * 4);
  float* h2m  = (float*)alloc((size_t)NN * DDIM * 4);
  u16*   f1b  = (u16*)alloc((size_t)NN * FF * 2);
  u16*   f2b  = (u16*)alloc((size_t)NN * FF * 2);
  u16*   h1b  = (u16*)alloc((size_t)NN * DDIM * 2);
  u16*   h2b  = (u16*)alloc((size_t)NN * DDIM * 2);
  u16*   h1t  = (u16*)alloc((size_t)NN * DDIM * 2);
  u16*   h2t  = (u16*)alloc((size_t)NN * DDIM * 2);
  u16*   wh1t = (u16*)alloc((size_t)NN * DDIM * 2);
  u16*   wh2t = (u16*)alloc((size_t)NN * DDIM * 2);
  u16*   mb0  = (u16*)alloc((size_t)NN * DDIM * 2);
  u16*   mb1  = (u16*)alloc((size_t)NN * DDIM * 2);
  u16*   mb2  = (u16*)alloc((size_t)NN * DDIM * 2);
  u16*   mb3  = (u16*)alloc((size_t)NN * DDIM * 2);
  u16*   mb4  = (u16*)alloc((size_t)NN * DDIM * 2);
  u16*   mb5  = (u16*)alloc((size_t)NN * DDIM * 2);
  float* alpha= (float*)alloc((size_t)ET * 4);
  int*   srcs = (int*)alloc((size_t)ET * 4);
  int*   deg  = (int*)alloc(NN * 4);
  int*   curs = (int*)alloc(NN * 4);
  int*   offs = (int*)alloc((NN + 1) * 4);
  float* n1inv= (float*)alloc(NN * 4);
  float* n2inv= (float*)alloc(NN * 4);
  float* Rr   = (float*)alloc(NN * 4);
  float* Ss   = (float*)alloc(NN * 4);
  float* scj1 = (float*)alloc(NN * 4);
  float* scj2 = (float*)alloc(NN * 4);
  float* hsb  = (float*)alloc(NN * 4);      // hsb,hdb adjacent: one memset
  float* hdb  = (float*)alloc(NN * 4);
  float* W2   = (float*)alloc((size_t)DDIM * DDIM * 4);
  u16*   Wg1t = (u16*)alloc((size_t)HH * FF * 2);
  u16*   Wg2t = (u16*)alloc((size_t)DDIM * HH * 2);
  u16*   W2t  = (u16*)alloc((size_t)DDIM * DDIM * 2);
  u16*   Mb   = (u16*)alloc(2 * 65536 * 2);
  // contiguous zeroed region (one memset): mug1|ogs|mug2|v|ut|Mf
  float* mug1 = (float*)alloc(4 * 256 * 4);
  float* ogs  = (float*)alloc(4 * 256 * 4);
  float* mug2 = (float*)alloc(6 * 256 * 4);
  float* v    = (float*)alloc(2048 * 4);
  float* ut   = (float*)alloc(512 * 4);
  float* Mf   = (float*)alloc(2 * 65536 * 4);
  float* g1   = (float*)alloc(4 * 256 * 4);
  float* g2   = (float*)alloc(6 * 256 * 4);
  float* l1o  = (float*)alloc(512 * 4);
  float* l2o  = (float*)alloc(256 * 4);
  float* l3o  = (float*)alloc(128 * 4);
  if (off > ws_size) return;

  float* h1g  = ogs + 0;
  float* h2g  = ogs + 256;
  float* h1mg = ogs + 512;
  float* h2mg = ogs + 768;
  const size_t zr_bytes = (4 * 256 + 4 * 256 + 6 * 256 + 2048 + 512 + 2 * 65536) * 4;

  // ---- stage 0 ----
  hipMemsetAsync(dsum, 0, 4 * sizeof(double), stream);
  k_reduce2<<<dim3(1024, 2), 256, 0, stream>>>(x_s, x_t, NN * FF, dsum);
  k_normalize2<<<dim3(1024, 2), 256, 0, stream>>>(x_s, x_t, f1b, f2b, NN * FF, dsum);

  // ---- weight preps ----
  k_tr_bf16<<<dim3(HH / 32, FF / 32), 256, 0, stream>>>(W_g1, Wg1t, FF, HH, 0);
  k_tr_bf16<<<dim3(DDIM / 32, HH / 32), 256, 0, stream>>>(W_g2, Wg2t, HH, DDIM, 0);
  k_tr_bf16<<<dim3(DDIM / 32, DDIM / 32), 256, 0, stream>>>(W_match, W2t, DDIM, DDIM, 1);
  k_w2<<<dim3((DDIM * DDIM + 255) / 256), 256, 0, stream>>>(W_match, W2, DDIM * DDIM);

  // ---- GAT ----
  auto run_gat = [&](const u16* finb, const int* ei, float* hout, u16* houtb) {
    hipMemsetAsync(deg, 0, NN * 4, stream);
    k_hist<<<dim3((ET + 255) / 256), 256, 0, stream>>>(ei, deg);
    k_scan<<<1, 256, 0, stream>>>(deg, offs, curs);
    k_scatter<<<dim3((ET + 255) / 256), 256, 0, stream>>>(ei, curs, srcs);
    hipMemsetAsync(hsb, 0, 2 * NN * 4, stream);
    k_gemm_bf<<<dim3(HH / 128, NN / 64), 256, 0, stream>>>(finb, Wg1t, hb_bf, FF, HH, a1s, a1d, hsb, hdb);
    k_alpha<<<dim3(NN / 4), 256, 0, stream>>>(offs, srcs, hsb, hdb, alpha);
    k_agg2<<<dim3(NN), 256, 0, stream>>>(offs, srcs, alpha, hb_bf, nullptr, aggb, HH, 1);
    hipMemsetAsync(hsb, 0, 2 * NN * 4, stream);
    k_gemm_bf<<<dim3(DDIM / 128, NN / 64), 256, 0, stream>>>(aggb, Wg2t, hb_bf, HH, DDIM, a2s, a2d, hsb, hdb);
    k_alpha<<<dim3(NN / 4), 256, 0, stream>>>(offs, srcs, hsb, hdb, alpha);
    k_agg2<<<dim3(NN), 256, 0, stream>>>(offs, srcs, alpha, hb_bf, hout, houtb, DDIM, 0);
  };
  run_gat(f1b, ei_s, h1, h1b);
  run_gat(f2b, ei_t, h2, h2b);

  // ---- mutual (rank-256 collapse) ----
  // R[i] = n1inv[i]*dot(h1_i, t); S[j] = n2inv[j]*dot(h2_j, u);
  // h1m = diag(n1inv) h1 (h2^T diag(n2inv/S) h2);  h2m = diag(n2inv) h2 (h1^T diag(n1inv/R) h1)
  k_rninv2<<<dim3(NN / 4, 2), 256, 0, stream>>>(h1, h2, n1inv, n2inv);
  hipMemsetAsync(mug1, 0, zr_bytes, stream);
  k_wsum<<<dim3(64, 2), 256, 0, stream>>>(h1, h2, n1inv, n2inv, ut);
  k_rs<<<dim3(NN / 4, 2), 256, 0, stream>>>(h1, h2, n1inv, n2inv, ut, Rr, Ss);
  k_scj<<<dim3(NN / 256), 256, 0, stream>>>(Ss, Rr, n1inv, n2inv, scj1, scj2);
  k_tr2w<<<dim3(DDIM / 32, NN / 32, 2), 256, 0, stream>>>(h2, scj1, h2t, wh2t, h1, scj2, h1t, wh1t);
  k_gemm_M<<<dim3(2, 4, 32), 256, 0, stream>>>(wh2t, h2t, wh1t, h1t, Mf);
  k_m2bf<<<dim3(256, 2), 256, 0, stream>>>(Mf, Mb);
  k_gemm_hm<<<dim3(2, 128, 2), 256, 0, stream>>>(h1b, Mb, n1inv, h1m,
                                                 h2b, Mb + 65536, n2inv, h2m);

  // ---- readout group 1: h1, h2, h1m, h2m ----
  PLF g1l; g1l.p[0] = h1; g1l.p[1] = h2; g1l.p[2] = h1m; g1l.p[3] = h2m;
  k_bmu_f<<<dim3(64, 4), 256, 0, stream>>>(g1l, mug1);
  k_bgv<<<dim3(4), 256, 0, stream>>>(mug1, W_read, g1);
  k_bsc_f<<<dim3(256, 4), 256, 0, stream>>>(g1l, g1, ogs);

  // ---- matches (batched) ----
  MB6 m6;
  m6.X[0] = h1;  m6.Y[0] = h1m;  m6.bx[0] = 0; m6.by[0] = 0; m6.o[0] = mb0;
  m6.X[1] = h1;  m6.Y[1] = h1mg; m6.bx[1] = 0; m6.by[1] = 1; m6.o[1] = mb1;
  m6.X[2] = h1g; m6.Y[2] = h1m;  m6.bx[2] = 1; m6.by[2] = 0; m6.o[2] = mb2;
  m6.X[3] = h2;  m6.Y[3] = h2m;  m6.bx[3] = 0; m6.by[3] = 0; m6.o[3] = mb3;
  m6.X[4] = h2;  m6.Y[4] = h2mg; m6.bx[4] = 0; m6.by[4] = 1; m6.o[4] = mb4;
  m6.X[5] = h2g; m6.Y[5] = h2m;  m6.bx[5] = 1; m6.by[5] = 0; m6.o[5] = mb5;
  k_match_b6<<<dim3(2, NN / 64, 6), 256, 0, stream>>>(m6, W2t);
  k_match_g<<<dim3(2), 256, 0, stream>>>(h1g, h1mg, h2g, h2mg, W2, v);

  // ---- readout group 2: 6 bf16 match outputs -> v slots ----
  PLB g2l;
  g2l.p[0] = mb0; g2l.slot[0] = 0;
  g2l.p[1] = mb1; g2l.slot[1] = 256;
  g2l.p[2] = mb2; g2l.slot[2] = 512;
  g2l.p[3] = mb3; g2l.slot[3] = 1024;
  g2l.p[4] = mb4; g2l.slot[4] = 1280;
  g2l.p[5] = mb5; g2l.slot[5] = 1536;
  k_bmu_b<<<dim3(64, 6), 256, 0, stream>>>(g2l, mug2);
  k_bgv<<<dim3(6), 256, 0, stream>>>(mug2, W_read, g2);
  k_bsc_b<<<dim3(256, 6), 256, 0, stream>>>(g2l, g2, v);

  // ---- MLP (split-K gemv) ----
  k_binit<<<dim3(2), 256, 0, stream>>>(b1, b2, b3, l1o, l2o, l3o);
  k_gemv<<<dim3(2, 16), 256, 0, stream>>>(v, w1, l1o, 2048, 512, 128, 0);
  k_gemv<<<dim3(1, 8), 256, 0, stream>>>(l1o, w2, l2o, 512, 256, 64, 1);
  k_gemv<<<dim3(1, 8), 256, 0, stream>>>(l2o, w3, l3o, 256, 128, 32, 1);
  k_final<<<1, 128, 0, stream>>>(l3o, w4, b4, label, out);
}